// Round 2
// baseline (1095.154 us; speedup 1.0000x reference)
//
#include <hip/hip_runtime.h>
#include <stdint.h>

// Product2Vec on MI355X (gfx950). B=2048, N=128, D=512, HID=2048, H=8, DH=64.
// Runtime-adaptive input dtype (bf16 vs fp32) via device-side sniffer.
//
// Math restructure (single-query MHA):
//   qt[b,h,d]   = sum_e q'[b,h*64+e] * Wk[d, h*64+e],  q' = (emb@Wq+bq)/8
//   scores      = nb . qt      (q.bk shift is softmax-invariant -> dropped)
//   ctxraw[b,h] = attn @ nb[b]
//   ctx[b,h*64+j] = ctxraw[b,h,:] @ Wv[:, h*64+j] + bv   (sum attn = 1)
//   out = ctx @ Wo + bo

typedef unsigned short u16;
typedef unsigned int u32;
typedef __attribute__((ext_vector_type(8))) short bf16x8;   // 8 bf16 (4 VGPRs)
typedef __attribute__((ext_vector_type(4))) float f32x4;

__device__ __forceinline__ float b2f(u16 h){
  union { u32 u; float f; } c; c.u = ((u32)h) << 16; return c.f;
}
__device__ __forceinline__ u16 f2b(float f){
  union { float f; u32 u; } c; c.f = f;
  u32 r = (c.u + 0x7fffu + ((c.u >> 16) & 1u)) >> 16;
  return (u16)r;
}
__device__ __forceinline__ float fast_tanh(float x){
  float ax = fabsf(x);
  float e  = __expf(2.0f * ax);
  float t  = 1.0f - 2.0f / (e + 1.0f);
  return x < 0.0f ? -t : t;
}
__device__ __forceinline__ void gl_lds16(const u16* g, u16* l){
  __builtin_amdgcn_global_load_lds((const __attribute__((address_space(1))) void*)g,
                                   (__attribute__((address_space(3))) void*)l,
                                   16, 0, 0);
}
__device__ __forceinline__ bool isf32(const int* flg){ return *flg > 32; }

// ------------- dtype sniffer: fp32 read as u16 -> ~12.5% exp>=0xC0; bf16 -> 0
__global__ void detect_kernel(const u16* w, int* flag){
  __shared__ int cnt[256];
  int c = 0;
  #pragma unroll
  for (int i = 0; i < 16; ++i){
    u16 v = w[threadIdx.x * 16 + i];
    if (((v >> 7) & 0xff) >= 0xC0) c++;
  }
  cnt[threadIdx.x] = c;
  __syncthreads();
  if (threadIdx.x == 0){
    int s = 0;
    for (int i = 0; i < 256; ++i) s += cnt[i];
    *flag = s;
  }
}

// ------------- adaptive copy to bf16 (4 elems/thread)
__global__ __launch_bounds__(256) void conv_copy(
    const void* __restrict__ src, u16* __restrict__ dst, int n4, const int* flg)
{
  int i = blockIdx.x * 256 + threadIdx.x;
  if (i >= n4) return;
  if (isf32(flg)){
    float4 v = ((const float4*)src)[i];
    ushort4 o; o.x = f2b(v.x); o.y = f2b(v.y); o.z = f2b(v.z); o.w = f2b(v.w);
    ((ushort4*)dst)[i] = o;
  } else {
    ((ushort4*)dst)[i] = ((const ushort4*)src)[i];
  }
}

// ------------- adaptive transpose to bf16: out[C][R] = in[R][C]
__global__ __launch_bounds__(256) void conv_transpose(
    const void* __restrict__ in, u16* __restrict__ out, int R, int Cc, const int* flg)
{
  __shared__ u16 t[32][33];
  int c0 = blockIdx.x * 32, r0 = blockIdx.y * 32;
  int lr = threadIdx.x >> 5, lc = threadIdx.x & 31;
  bool f = isf32(flg);
  #pragma unroll
  for (int p = 0; p < 4; ++p){
    int r = p * 8 + lr;
    size_t idx = (size_t)(r0 + r) * Cc + c0 + lc;
    t[r][lc] = f ? f2b(((const float*)in)[idx]) : ((const u16*)in)[idx];
  }
  __syncthreads();
  #pragma unroll
  for (int p = 0; p < 4; ++p){
    int c = p * 8 + lr;
    out[(size_t)(c0 + c) * R + r0 + lc] = t[lc][c];
  }
}

// ---------------- bf16 GEMM: C = epi(A @ Bt^T + bias) ----------------
// A [M][lda] (k contig), Bt [N][ldb] (k contig), C [M][ldc]. 128 x (NT*32) tile,
// BK=32, 256 thr = 4 waves (2x2). epi: 0=+bias, 1=tanh, 2=*0.125. outflg: f32 C.
template<int NT>
__global__ __launch_bounds__(256) void gemm_bt(
    const u16* __restrict__ A, int lda,
    const u16* __restrict__ Bt, int ldb,
    u16* __restrict__ C, int ldc,
    const u16* __restrict__ bias,
    int K, int epi,
    int aOffZ, int bOffZ, int cOffZ, int biasOffZ,
    const int* outflg)
{
  constexpr int BN2 = NT * 16;
  __shared__ u16 As[128 * 32];
  __shared__ u16 Bs[NT * 32 * 32];
  const int z = blockIdx.z;
  A  += (size_t)z * aOffZ;
  Bt += (size_t)z * bOffZ;
  C  += (size_t)z * cOffZ;
  if (bias) bias += z * biasOffZ;

  const int tid = threadIdx.x;
  const int w = tid >> 6, l = tid & 63;
  const int wm = w & 1, wn = w >> 1;
  const int m0 = blockIdx.x * 128;
  const int n0 = blockIdx.y * (NT * 32);
  const int l15 = l & 15;
  const int kq  = (l >> 4) * 8;

  f32x4 acc[4][NT];
  #pragma unroll
  for (int i = 0; i < 4; ++i)
    #pragma unroll
    for (int j = 0; j < NT; ++j)
      acc[i][j] = (f32x4){0.f, 0.f, 0.f, 0.f};

  const int nkt = K >> 5;
  for (int kt = 0; kt < nkt; ++kt){
    const int k0 = kt << 5;
    __syncthreads();
    #pragma unroll
    for (int it = 0; it < 2; ++it){
      int e = (it * 4 + w) * 512 + l * 8;
      gl_lds16(A + (size_t)(m0 + (e >> 5)) * lda + k0 + (e & 31), &As[e]);
    }
    #pragma unroll
    for (int it = 0; it < NT / 2; ++it){
      int e = (it * 4 + w) * 512 + l * 8;
      gl_lds16(Bt + (size_t)(n0 + (e >> 5)) * ldb + k0 + (e & 31), &Bs[e]);
    }
    __syncthreads();
    bf16x8 af[4], bfr[NT];
    #pragma unroll
    for (int mt = 0; mt < 4; ++mt)
      af[mt] = *(const bf16x8*)&As[(wm * 64 + mt * 16 + l15) * 32 + kq];
    #pragma unroll
    for (int nt = 0; nt < NT; ++nt)
      bfr[nt] = *(const bf16x8*)&Bs[(wn * BN2 + nt * 16 + l15) * 32 + kq];
    #pragma unroll
    for (int mt = 0; mt < 4; ++mt)
      #pragma unroll
      for (int nt = 0; nt < NT; ++nt)
        acc[mt][nt] = __builtin_amdgcn_mfma_f32_16x16x32_bf16(af[mt], bfr[nt], acc[mt][nt], 0, 0, 0);
  }

  const bool f32o = outflg && isf32(outflg);
  const int q4 = (l >> 4) * 4;
  #pragma unroll
  for (int nt = 0; nt < NT; ++nt){
    int n = n0 + wn * BN2 + nt * 16 + l15;
    float bb = bias ? b2f(bias[n]) : 0.0f;
    #pragma unroll
    for (int mt = 0; mt < 4; ++mt){
      #pragma unroll
      for (int r = 0; r < 4; ++r){
        int m = m0 + wm * 64 + mt * 16 + q4 + r;
        float x = acc[mt][nt][r] + bb;
        if (epi == 1) x = fast_tanh(x);
        else if (epi == 2) x *= 0.125f;
        if (f32o) ((float*)C)[(size_t)m * ldc + n] = x;
        else      C[(size_t)m * ldc + n] = f2b(x);
      }
    }
  }
}

// ---------------- BatchNorm over B=2048 rows of X[2048][2048] ----------------
__global__ __launch_bounds__(256) void bn_stats(
    const u16* __restrict__ X, float* __restrict__ s1, float* __restrict__ s2)
{
  int c  = blockIdx.x * 256 + threadIdx.x;
  int r0 = blockIdx.y * 256;
  float a = 0.f, b = 0.f;
  for (int r = 0; r < 256; ++r){
    float x = b2f(X[(size_t)(r0 + r) * 2048 + c]);
    a += x; b += x * x;
  }
  atomicAdd(&s1[c], a);
  atomicAdd(&s2[c], b);
}

__global__ __launch_bounds__(256) void bn_fin(
    const float* __restrict__ s1, const float* __restrict__ s2,
    const u16* __restrict__ gamma, const u16* __restrict__ beta,
    float* __restrict__ A, float* __restrict__ Cc)
{
  int j = blockIdx.x * 256 + threadIdx.x;
  float mu  = s1[j] * (1.0f / 2048.0f);
  float var = s2[j] * (1.0f / 2048.0f) - mu * mu;
  float a = b2f(gamma[j]) * rsqrtf(var + 1e-5f);
  A[j]  = a;
  Cc[j] = b2f(beta[j]) - mu * a;
}

__global__ __launch_bounds__(256) void bn_apply(
    u16* __restrict__ X, const float* __restrict__ A, const float* __restrict__ Cc)
{
  int i = blockIdx.x * 256 + threadIdx.x;
  uint4 v = ((const uint4*)X)[i];
  u16* p = (u16*)&v;
  int base = i * 8;
  #pragma unroll
  for (int e = 0; e < 8; ++e){
    int j = (base + e) & 2047;
    p[e] = f2b(A[j] * b2f(p[e]) + Cc[j]);
  }
  ((uint4*)X)[i] = v;
}

// ---------------- attention part 1: scores + softmax -> attn [B][8][128] bf16
// LDS: qtS 16x264 (8.4KB) + nbS 64x264 (33.8KB) + scS 128x17 f32 (8.7KB) = 51KB
__global__ __launch_bounds__(256) void att_scores(
    const void* __restrict__ nb_g, const int* __restrict__ lengths,
    const u16* __restrict__ qt_g, u16* __restrict__ attn_g, const int* flg)
{
  __shared__ u16 qtS[16 * 264];
  __shared__ u16 nbS[64 * 264];
  __shared__ float scS[128 * 17];
  const int b = blockIdx.x, tid = threadIdx.x;
  const int w = tid >> 6, l = tid & 63;
  const int l15 = l & 15, kq = (l >> 4) * 8;
  const bool f = isf32(flg);

  for (int n0c = 0; n0c < 2; ++n0c){
    f32x4 acc = (f32x4){0.f, 0.f, 0.f, 0.f};
    for (int dh = 0; dh < 2; ++dh){
      __syncthreads();
      { // qt stage: rows 0..7 real, rows 8..15 zero; cols dh*256..+255
        int row = tid >> 5, col8 = (tid & 31) * 8;
        *(uint4*)&qtS[row * 264 + col8] =
            *(const uint4*)&qt_g[(size_t)b * 4096 + row * 512 + dh * 256 + col8];
        uint4 zz; zz.x = zz.y = zz.z = zz.w = 0u;
        *(uint4*)&qtS[(8 + row) * 264 + col8] = zz;
      }
      #pragma unroll
      for (int it = 0; it < 8; ++it){ // nb stage: 64 rows x 256 cols
        int c = it * 256 + tid, row = c >> 5, col8 = (c & 31) * 8;
        size_t base = (size_t)b * 65536 + (size_t)(n0c * 64 + row) * 512 + dh * 256 + col8;
        uint4 v;
        if (f){
          float4 a  = *(const float4*)((const float*)nb_g + base);
          float4 bb = *(const float4*)((const float*)nb_g + base + 4);
          u16* p = (u16*)&v;
          p[0]=f2b(a.x); p[1]=f2b(a.y); p[2]=f2b(a.z); p[3]=f2b(a.w);
          p[4]=f2b(bb.x);p[5]=f2b(bb.y);p[6]=f2b(bb.z);p[7]=f2b(bb.w);
        } else {
          v = *(const uint4*)((const u16*)nb_g + base);
        }
        *(uint4*)&nbS[row * 264 + col8] = v;
      }
      __syncthreads();
      const int n = w * 16 + l15;
      #pragma unroll
      for (int ks = 0; ks < 8; ++ks){
        bf16x8 a  = *(const bf16x8*)&nbS[n * 264 + ks * 32 + kq];
        bf16x8 q8 = *(const bf16x8*)&qtS[l15 * 264 + ks * 32 + kq];
        acc = __builtin_amdgcn_mfma_f32_16x16x32_bf16(a, q8, acc, 0, 0, 0);
      }
    }
    const int q4 = (l >> 4) * 4;
    #pragma unroll
    for (int r = 0; r < 4; ++r)
      scS[(n0c * 64 + w * 16 + q4 + r) * 17 + l15] = acc[r];
  }
  __syncthreads();

  const int len = lengths[b];
  #pragma unroll
  for (int hp = 0; hp < 2; ++hp){
    int h = w + hp * 4;
    float s0 = scS[l * 17 + h], s1 = scS[(64 + l) * 17 + h];
    float m0 = (l < len)      ? s0 : -3.0e38f;
    float m1 = (64 + l < len) ? s1 : -3.0e38f;
    float m = fmaxf(m0, m1);
    #pragma unroll
    for (int o = 32; o > 0; o >>= 1) m = fmaxf(m, __shfl_xor(m, o, 64));
    float e0 = (l < len)      ? __expf(s0 - m) : 0.0f;
    float e1 = (64 + l < len) ? __expf(s1 - m) : 0.0f;
    float s = e0 + e1;
    #pragma unroll
    for (int o = 32; o > 0; o >>= 1) s += __shfl_xor(s, o, 64);
    float inv = 1.0f / s;
    attn_g[(size_t)b * 1024 + h * 128 + l]      = f2b(e0 * inv);
    attn_g[(size_t)b * 1024 + h * 128 + 64 + l] = f2b(e1 * inv);
  }
}

// ---------------- attention part 2: ctxraw[b,h,d] = sum_n attn*nb (VALU)
// 256 thr, thread owns d=tid and d=tid+256. LDS: atF 4KB + nbS 32x512 (32KB)
__global__ __launch_bounds__(256) void att_pv(
    const void* __restrict__ nb_g, const u16* __restrict__ attn_g,
    u16* __restrict__ ctxr_g, const int* flg)
{
  __shared__ float atF[1024];
  __shared__ u16 nbS[32 * 512];
  const int b = blockIdx.x, tid = threadIdx.x;
  const bool f = isf32(flg);
  #pragma unroll
  for (int it = 0; it < 4; ++it){
    int i = it * 256 + tid;
    atF[i] = b2f(attn_g[(size_t)b * 1024 + i]);
  }
  float acc[16];
  #pragma unroll
  for (int i = 0; i < 16; ++i) acc[i] = 0.f;

  for (int n0 = 0; n0 < 128; n0 += 32){
    __syncthreads();
    #pragma unroll
    for (int it = 0; it < 8; ++it){
      int c = it * 256 + tid, row = c >> 6, col8 = (c & 63) * 8;
      size_t base = (size_t)b * 65536 + (size_t)(n0 + row) * 512 + col8;
      uint4 v;
      if (f){
        float4 a  = *(const float4*)((const float*)nb_g + base);
        float4 bb = *(const float4*)((const float*)nb_g + base + 4);
        u16* p = (u16*)&v;
        p[0]=f2b(a.x); p[1]=f2b(a.y); p[2]=f2b(a.z); p[3]=f2b(a.w);
        p[4]=f2b(bb.x);p[5]=f2b(bb.y);p[6]=f2b(bb.z);p[7]=f2b(bb.w);
      } else {
        v = *(const uint4*)((const u16*)nb_g + base);
      }
      *(uint4*)&nbS[row * 512 + col8] = v;
    }
    __syncthreads();
    #pragma unroll 4
    for (int n = 0; n < 32; ++n){
      float v0 = b2f(nbS[n * 512 + tid]);
      float v1 = b2f(nbS[n * 512 + 256 + tid]);
      #pragma unroll
      for (int h = 0; h < 8; ++h){
        float a = atF[h * 128 + n0 + n];
        acc[h]     += a * v0;
        acc[8 + h] += a * v1;
      }
    }
  }
  #pragma unroll
  for (int h = 0; h < 8; ++h){
    ctxr_g[(size_t)b * 4096 + h * 512 + tid]       = f2b(acc[h]);
    ctxr_g[(size_t)b * 4096 + h * 512 + 256 + tid] = f2b(acc[8 + h]);
  }
}

// ---------------- host ----------------
extern "C" void kernel_launch(void* const* d_in, const int* in_sizes, int n_in,
                              void* d_out, int out_size, void* d_ws, size_t ws_size,
                              hipStream_t stream)
{
  (void)in_sizes; (void)n_in; (void)out_size; (void)ws_size;
  const void* cat   = d_in[0];
  const void* nbg   = d_in[1];
  const int*  len   = (const int*)d_in[2];
  const void* W1    = d_in[3];
  const void* b1    = d_in[4];
  const void* gamma = d_in[5];
  const void* beta  = d_in[6];
  const void* W2    = d_in[7];
  const void* b2    = d_in[8];
  const void* W3    = d_in[9];
  const void* b3    = d_in[10];
  const void* Wq    = d_in[11];
  const void* bq    = d_in[12];
  const void* Wk    = d_in[13];
  // d_in[14] = bk: softmax-invariant score shift, unused
  const void* Wv    = d_in[15];
  const void* bv    = d_in[16];
  const void* Wo    = d_in[17];
  const void* bo    = d_in[18];

  char* ws = (char*)d_ws;
  u16* X1   = (u16*)(ws + 0);          // [2048][2048]; qt/ctxr alias [0,16MB)
  u16* X2   = (u16*)(ws + 8388608);
  u16* qt   = (u16*)(ws + 0);          // [2048][8][512] after X1/X2 dead
  u16* ctxr = qt;
  u16* emb  = (u16*)(ws + 16777216);   // [2048][512]
  u16* q    = (u16*)(ws + 18874368);   // [2048][512]
  u16* ctx  = (u16*)(ws + 20971520);   // [2048][512]
  u16* attn = (u16*)(ws + 23068672);   // [2048][8][128]
  u16* catB = (u16*)(ws + 27262976);   // [2048][512]
  u16* WkB  = (u16*)(ws + 29360128);   // [512][512]
  u16* W1T  = (u16*)(ws + 29884416);   // [2048][512]
  u16* W2T  = (u16*)(ws + 31981568);   // [2048][2048]
  u16* W3T  = (u16*)(ws + 40370176);   // [512][2048]
  u16* WqT  = (u16*)(ws + 42467328);   // [512][512]
  u16* WvT  = (u16*)(ws + 42991616);
  u16* WoT  = (u16*)(ws + 43515904);
  u16* bB   = (u16*)(ws + 44040192);   // b1,gamma,beta,b2 (2048 ea) b3,bq,bv,bo (512 ea)
  float* s1 = (float*)(ws + 44060672);
  float* s2 = (float*)(ws + 44068864);
  float* bnA= (float*)(ws + 44077056);
  float* bnC= (float*)(ws + 44085248);
  int* flag = (int*)(ws + 44093440);

  u16 *b1B = bB, *gmB = bB + 2048, *btB = bB + 4096, *b2B = bB + 6144;
  u16 *b3B = bB + 8192, *bqB = bB + 8704, *bvB = bB + 9216, *boB = bB + 9728;

  detect_kernel<<<1, 256, 0, stream>>>((const u16*)W1, flag);

  conv_copy<<<1024, 256, 0, stream>>>(cat, catB, 262144, flag);
  conv_copy<<<256, 256, 0, stream>>>(Wk, WkB, 65536, flag);
  conv_copy<<<2, 256, 0, stream>>>(b1, b1B, 512, flag);
  conv_copy<<<2, 256, 0, stream>>>(gamma, gmB, 512, flag);
  conv_copy<<<2, 256, 0, stream>>>(beta, btB, 512, flag);
  conv_copy<<<2, 256, 0, stream>>>(b2, b2B, 512, flag);
  conv_copy<<<1, 256, 0, stream>>>(b3, b3B, 128, flag);
  conv_copy<<<1, 256, 0, stream>>>(bq, bqB, 128, flag);
  conv_copy<<<1, 256, 0, stream>>>(bv, bvB, 128, flag);
  conv_copy<<<1, 256, 0, stream>>>(bo, boB, 128, flag);

  conv_transpose<<<dim3(64, 16), 256, 0, stream>>>(W1, W1T, 512, 2048, flag);
  conv_transpose<<<dim3(64, 64), 256, 0, stream>>>(W2, W2T, 2048, 2048, flag);
  conv_transpose<<<dim3(16, 64), 256, 0, stream>>>(W3, W3T, 2048, 512, flag);
  conv_transpose<<<dim3(16, 16), 256, 0, stream>>>(Wq, WqT, 512, 512, flag);
  conv_transpose<<<dim3(16, 16), 256, 0, stream>>>(Wv, WvT, 512, 512, flag);
  conv_transpose<<<dim3(16, 16), 256, 0, stream>>>(Wo, WoT, 512, 512, flag);

  hipMemsetAsync(s1, 0, 16384, stream);  // s1 + s2

  // FFN
  gemm_bt<4><<<dim3(16, 16), 256, 0, stream>>>(catB, 512, W1T, 512, X1, 2048, b1B, 512, 1, 0, 0, 0, 0, nullptr);
  bn_stats<<<dim3(8, 8), 256, 0, stream>>>(X1, s1, s2);
  bn_fin  <<<8, 256, 0, stream>>>(s1, s2, gmB, btB, bnA, bnC);
  bn_apply<<<2048, 256, 0, stream>>>(X1, bnA, bnC);
  gemm_bt<4><<<dim3(16, 16), 256, 0, stream>>>(X1, 2048, W2T, 2048, X2, 2048, b2B, 2048, 1, 0, 0, 0, 0, nullptr);
  gemm_bt<4><<<dim3(16, 4), 256, 0, stream>>>(X2, 2048, W3T, 2048, emb, 512, b3B, 2048, 0, 0, 0, 0, 0, nullptr);

  // q' = (emb@Wq + bq)/8 ; qt[b,h,:] = q'[b,h-slice] @ Wk[:,h-slice]^T (grid.z = head)
  gemm_bt<4><<<dim3(16, 4), 256, 0, stream>>>(emb, 512, WqT, 512, q, 512, bqB, 512, 2, 0, 0, 0, 0, nullptr);
  gemm_bt<4><<<dim3(16, 4, 8), 256, 0, stream>>>(q, 512, WkB, 512, qt, 4096, nullptr, 64, 0, 64, 64, 512, 0, nullptr);

  // attention
  att_scores<<<2048, 256, 0, stream>>>(nbg, len, qt, attn, flag);
  att_pv<<<2048, 256, 0, stream>>>(nbg, attn, ctxr, flag);

  // ctx[b, h-slice] = ctxraw[b,h,:] @ Wv[:, h-slice] + bv  (grid.z = head)
  gemm_bt<2><<<dim3(16, 1, 8), 256, 0, stream>>>(ctxr, 4096, WvT, 512, ctx, 512, bvB, 512, 0, 512, 32768, 64, 64, nullptr);

  // out = ctx @ Wo + bo (adaptive output dtype)
  gemm_bt<4><<<dim3(16, 4), 256, 0, stream>>>(ctx, 512, WoT, 512, (u16*)d_out, 512, boB, 512, 0, 0, 0, 0, 0, flag);
}